// Round 7
// baseline (478.838 us; speedup 1.0000x reference)
//
#include <hip/hip_runtime.h>
#include <hip/hip_bf16.h>
#include <stdint.h>

typedef __bf16 bf16;
typedef __bf16 bf16x8 __attribute__((ext_vector_type(8)));
typedef __bf16 bf16x4 __attribute__((ext_vector_type(4)));
typedef float f32x4 __attribute__((ext_vector_type(4)));
typedef float f32x16 __attribute__((ext_vector_type(16)));

#define B_ 2
#define L_ 2048
#define E_ 2048
#define H_ 16
#define HKV_ 2
#define G_ 8
#define D_ 128
#define SPAST_ 2048
#define S_ 4096
#define EKV_ 256

#define MFMA16(a, b, c) __builtin_amdgcn_mfma_f32_16x16x32_bf16(a, b, c, 0, 0, 0)
#define MFMA32(a, b, c) __builtin_amdgcn_mfma_f32_32x32x16_bf16(a, b, c, 0, 0, 0)

__device__ __forceinline__ void gload16(const bf16* g, bf16* l) {
  __builtin_amdgcn_global_load_lds(
      (__attribute__((address_space(1))) void*)g,
      (__attribute__((address_space(3))) void*)l, 16, 0, 0);
}

// ---------------- f32 -> bf16 conversion ----------------
__global__ void cvt_kernel(const float* __restrict__ src, bf16* __restrict__ dst, int n) {
  int i = (blockIdx.x * 256 + threadIdx.x) * 4;
  if (i >= n) return;
  float4 v = *(const float4*)(src + i);
  bf16x4 o;
  o[0] = (bf16)v.x; o[1] = (bf16)v.y; o[2] = (bf16)v.z; o[3] = (bf16)v.w;
  *(bf16x4*)(dst + i) = o;
}

// ---------------- trig table ----------------
__global__ void trig_kernel(const int* __restrict__ offp, float2* __restrict__ trig) {
  int l = blockIdx.x, j = threadIdx.x;  // 64 threads
  float inv = exp2f(-(float)j * (13.287712379549449f / 64.0f));  // log2(10000)
  float ang = (float)(*offp + l) * inv;
  trig[l * 64 + j] = make_float2(cosf(ang), sinf(ang));
}

// ---------------- NT GEMM: C(M,N) = A(M,K) @ Bw(N,K)^T + bias ----------------
template <int OUTF32>
__global__ __launch_bounds__(256) void gemm_nt(const bf16* __restrict__ A,
                                               const bf16* __restrict__ Bw,
                                               const float* __restrict__ bias,
                                               void* __restrict__ Cout,
                                               int M, int N, int K) {
  __shared__ bf16 As[128 * 64];
  __shared__ bf16 Bs[128 * 64];
  const int tid = threadIdx.x;
  const int wid = tid >> 6, lane = tid & 63;
  const int ln15 = lane & 15, lq = lane >> 4;
  const int row0 = blockIdx.x * 128, col0 = blockIdx.y * 128;
  const int wr = wid >> 1, wc = wid & 1;
  f32x4 acc[4][4] = {};
  char* AsB = (char*)As;
  char* BsB = (char*)Bs;
  for (int k0 = 0; k0 < K; k0 += 64) {
#pragma unroll
    for (int j = 0; j < 4; j++) {
      int cid = j * 256 + tid;
      int r = cid >> 3, c = cid & 7;
      int csw = (c ^ (r & 7)) << 3;
      gload16(A + (size_t)(row0 + r) * K + k0 + csw, (bf16*)(AsB + (j * 256 + wid * 64) * 16));
      gload16(Bw + (size_t)(col0 + r) * K + k0 + csw, (bf16*)(BsB + (j * 256 + wid * 64) * 16));
    }
    __syncthreads();
    bf16x8 af[4][2], bfm[4][2];
#pragma unroll
    for (int m = 0; m < 4; m++) {
#pragma unroll
      for (int kk = 0; kk < 2; kk++) {
        int Ra = wr * 64 + m * 16 + ln15;
        int Rb = wc * 64 + m * 16 + ln15;
        int c = (kk << 2) + lq;
        af[m][kk] = *(const bf16x8*)(AsB + Ra * 128 + ((c ^ (Ra & 7)) << 4));
        bfm[m][kk] = *(const bf16x8*)(BsB + Rb * 128 + ((c ^ (Rb & 7)) << 4));
      }
    }
#pragma unroll
    for (int m = 0; m < 4; m++)
#pragma unroll
      for (int n = 0; n < 4; n++)
#pragma unroll
        for (int kk = 0; kk < 2; kk++)
          acc[m][n] = MFMA16(af[m][kk], bfm[n][kk], acc[m][n]);
    __syncthreads();
  }
#pragma unroll
  for (int m = 0; m < 4; m++) {
    int gr0 = row0 + wr * 64 + m * 16 + 4 * lq;
#pragma unroll
    for (int n = 0; n < 4; n++) {
      int gc = col0 + wc * 64 + n * 16 + ln15;
      float bv = bias ? bias[gc] : 0.0f;
#pragma unroll
      for (int reg = 0; reg < 4; reg++) {
        float v = acc[m][n][reg] + bv;
        size_t idx = (size_t)(gr0 + reg) * N + gc;
        if (OUTF32)
          ((float*)Cout)[idx] = v;
        else
          ((bf16*)Cout)[idx] = (bf16)v;
      }
    }
  }
}

// ---------------- RoPE on Q (vectorized bf16x8), fold softmax scale*log2e ----------------
__global__ void rope_q_kernel(const bf16* __restrict__ q_lin, const float2* __restrict__ trig,
                              bf16* __restrict__ qbuf) {
  int bl = blockIdx.x * 2 + (threadIdx.x >> 7);  // grid = B*L/2
  int b = bl >> 11, l = bl & 2047;
  int u = threadIdx.x & 127;
  int h = u >> 3, j0 = (u & 7) * 8;
  const float QS = 0.08838834764831845f * 1.4426950408889634f;  // 1/sqrt(128) * log2(e)
  const bf16* src = q_lin + (size_t)bl * E_ + h * D_ + j0;
  bf16x8 x1 = *(const bf16x8*)(src);
  bf16x8 x2 = *(const bf16x8*)(src + 64);
  bf16x8 o1, o2;
#pragma unroll
  for (int e = 0; e < 8; e++) {
    float2 cs = trig[l * 64 + j0 + e];
    float a = (float)x1[e], c = (float)x2[e];
    o1[e] = (bf16)((a * cs.x - c * cs.y) * QS);
    o2[e] = (bf16)((c * cs.x + a * cs.y) * QS);
  }
  size_t o = ((size_t)(b * H_ + h) * L_ + l) * D_ + j0;
  *(bf16x8*)(qbuf + o) = o1;
  *(bf16x8*)(qbuf + o + 64) = o2;
}

// ---------------- build k_all (B,HKV,S,D) ----------------
__global__ void build_k_kernel(const float* __restrict__ k_cache, const bf16* __restrict__ k_lin,
                               const float2* __restrict__ trig, bf16* __restrict__ k_all) {
  int d = threadIdx.x;  // 128
  int s = blockIdx.x;
  int bz = blockIdx.y;  // b*HKV + hkv
  size_t oidx = ((size_t)bz * S_ + s) * D_ + d;
  if (s < SPAST_) {
    k_all[oidx] = (bf16)k_cache[((size_t)bz * SPAST_ + s) * D_ + d];
  } else {
    int l = s - SPAST_;
    int b = bz >> 1, kh = bz & 1;
    int j = d & 63;
    float2 cs = trig[l * 64 + j];
    size_t base = (size_t)(b * L_ + l) * EKV_ + kh * D_;
    float x1 = (float)k_lin[base + j];
    float x2 = (float)k_lin[base + 64 + j];
    float v = (d < 64) ? (x1 * cs.x - x2 * cs.y) : (x2 * cs.x + x1 * cs.y);
    k_all[oidx] = (bf16)v;
  }
}

// ---------------- build transposed V: vtall (B,HKV,D,S) (vectorized) ----------------
__global__ void build_vt_kernel(const float* __restrict__ v_cache, const bf16* __restrict__ v_lin,
                                bf16* __restrict__ vtall) {
  __shared__ float tile[64][68];
  int s0 = blockIdx.x * 64;
  int d0 = blockIdx.y * 64;
  int bz = blockIdx.z;
  int b = bz >> 1, kh = bz & 1;
#pragma unroll
  for (int it = 0; it < 4; it++) {
    int idx = it * 256 + threadIdx.x;  // 0..1023
    int ss = idx >> 4, dd0 = (idx & 15) * 4;
    int s = s0 + ss;
    float4 v;
    if (s < SPAST_) {
      v = *(const float4*)(v_cache + ((size_t)bz * SPAST_ + s) * D_ + d0 + dd0);
    } else {
      bf16x4 t = *(const bf16x4*)(v_lin + (size_t)(b * L_ + (s - SPAST_)) * EKV_ + kh * D_ + d0 + dd0);
      v = make_float4((float)t[0], (float)t[1], (float)t[2], (float)t[3]);
    }
    tile[ss][dd0] = v.x; tile[ss][dd0 + 1] = v.y;
    tile[ss][dd0 + 2] = v.z; tile[ss][dd0 + 3] = v.w;
  }
  __syncthreads();
#pragma unroll
  for (int it = 0; it < 4; it++) {
    int idx = it * 256 + threadIdx.x;
    int dd = idx >> 4, ss0 = (idx & 15) * 4;
    bf16x4 o;
#pragma unroll
    for (int e = 0; e < 4; e++) o[e] = (bf16)tile[ss0 + e][dd];
    *(bf16x4*)(vtall + ((size_t)bz * D_ + d0 + dd) * S_ + s0 + ss0) = o;
  }
}

// ---------------- flash attention: split-S 8-wave blocks, 32x32 MFMA, in-register P ----------------
// grid (16, 32) x 512 threads. Waves 0-3 (grp 0) process even 32-key chunks, waves 4-7 (grp 1)
// odd chunks, of the SAME 128 q-rows. Each group has its own dbuf K/V LDS stream (64KB total).
// 4096 waves = 4 waves/SIMD (vs 2 before) -> latency hiding. End: in-LDS merge of the two
// online-softmax partials (m,l,acc), group 0 stores.
__global__ __launch_bounds__(512, 4) void attn_kernel(const bf16* __restrict__ qbuf,
                                                      const bf16* __restrict__ k_all,
                                                      const bf16* __restrict__ vtall,
                                                      bf16* __restrict__ attnout) {
  __shared__ char ldsbuf[65536];     // [grp][K|V][buf][8KB]
  __shared__ float ml1[4][64][2];    // group-1 (m,l) for merge
  const int tid = threadIdx.x;
  const int wid = tid >> 6, lane = tid & 63;
  const int grp = wid >> 2, wid4 = wid & 3;
  const int l31 = lane & 31, h = lane >> 5;
  // balance remap: co-resident blocks (x,y),(x,y+16) -> q-blocks x, 15-x (constant sum)
  const int xq = ((blockIdx.y >> 4) & 1) ? (15 - (int)blockIdx.x) : (int)blockIdx.x;
  const int q0 = xq * 128;
  const int bh = blockIdx.y;
  const int b = bh / H_, hh = bh % H_;
  const int hkv = hh / G_;
  const bf16* kb = k_all + (size_t)(b * HKV_ + hkv) * S_ * D_;
  const bf16* vb = vtall + (size_t)(b * HKV_ + hkv) * D_ * S_;
  const int qw = q0 + wid4 * 32;  // wave's q base (groups share q-rows)
  // per-thread staging source rows (t8 = position within group)
  const int t8 = (wid4 << 6) | lane;            // 0..255
  const int r0 = t8 >> 4;                        // 0..15
  const int cl0 = (t8 & 15) ^ (r0 & 15);         // logical 16B slot
  const bf16* krow = kb + r0 * D_ + cl0 * 8;                           // + s0*D [+16*D]
  const bf16* vrow = vb + (size_t)(4 * r0 + (cl0 >> 2)) * S_ + (cl0 & 3) * 8;  // + s0 [+64*S]
  char* kbase = ldsbuf + grp * 16384;
  char* vbase = ldsbuf + 32768 + grp * 16384;
  const int dstoff = (wid4 * 64) * 16;
  // Q fragments (B operand): col=q=l31, k-dim d = ks*16 + 8h + i
  bf16x8 qf[8];
  {
    const bf16* qp = qbuf + ((size_t)(b * H_ + hh) * L_ + qw + l31) * D_ + h * 8;
#pragma unroll
    for (int ks = 0; ks < 8; ks++) qf[ks] = *(const bf16x8*)(qp + ks * 16);
  }
  f32x16 acc[4] = {};
  float mr = -3e38f, lr = 0.f;

  auto STAGE = [&](int buf, int s0) {
    char* kd = kbase + buf * 8192 + dstoff;
    char* vd = vbase + buf * 8192 + dstoff;
    size_t ko = (size_t)s0 << 7;  // s0 * D_
    gload16(krow + ko, (bf16*)(kd));
    gload16(krow + ko + 16 * D_, (bf16*)(kd + 4096));
    gload16(vrow + s0, (bf16*)(vd));
    gload16(vrow + s0 + (size_t)64 * S_, (bf16*)(vd + 4096));
  };

  const int nch = (q0 + 128 + SPAST_) >> 5;  // 32-key chunks; always even (68+4xq)
  const int rounds = nch >> 1;               // chunks per group
  const int smax_w = qw + 32 + SPAST_;

  STAGE(0, grp << 5);  // group g: chunk g
  __syncthreads();
  int cur = 0;
  for (int i = 0; i < rounds; ++i) {
    const int s0 = ((i << 1) + grp) << 5;
    if (i + 1 < rounds) STAGE(cur ^ 1, s0 + 64);  // prefetch own next chunk
    if (s0 < smax_w) {
      char* kcur = kbase + cur * 8192;
      char* vcur = vbase + cur * 8192;
      // ---- swapped QK^T: lane holds q=l31, keys s0 + (r&3)+8*(r>>2)+4h, r=0..15
      f32x16 st;
      {
        f32x16 a = {};
        __builtin_amdgcn_s_setprio(1);
#pragma unroll
        for (int ks = 0; ks < 8; ks++) {
          int cl = 2 * ks + h;
          bf16x8 kf = *(const bf16x8*)(kcur + l31 * 256 + ((cl ^ (l31 & 15)) << 4));
          a = MFMA32(kf, qf[ks], a);
        }
        __builtin_amdgcn_s_setprio(0);
        st = a;
      }
      // ---- causal mask (only diagonal chunks trigger)
      if (s0 + 31 > qw + SPAST_) {
        int q = qw + l31;
#pragma unroll
        for (int r = 0; r < 16; r++) {
          int key = s0 + (r & 3) + 8 * (r >> 2) + 4 * h;
          if (key > q + SPAST_) st[r] = -1e30f;
        }
      }
      // ---- online softmax: in-lane tree + 1 half-swap
      float mt = fmaxf(st[0], st[1]);
#pragma unroll
      for (int r = 2; r < 16; r++) mt = fmaxf(mt, st[r]);
      mt = fmaxf(mt, __shfl_xor(mt, 32));
      if (__any(mt - mr > 8.0f)) {  // T13 defer-max
        float mn = fmaxf(mr, mt);
        float fac = exp2f(mr - mn);
        mr = mn;
        lr *= fac;
#pragma unroll
        for (int dt = 0; dt < 4; dt++) acc[dt] *= fac;
      }
      float s = 0.f;
#pragma unroll
      for (int r = 0; r < 16; r++) {
        float p = exp2f(st[r] - mr);
        st[r] = p;
        s += p;
      }
      s += __shfl_xor(s, 32);
      lr += s;
      // ---- P -> bf16 dwords + permlane32_swap (VDST.hi <-> VSRC.lo)
      uint32_t W[8];
#pragma unroll
      for (int j = 0; j < 8; j++)
        asm("v_cvt_pk_bf16_f32 %0, %1, %2" : "=v"(W[j]) : "v"(st[2 * j]), "v"(st[2 * j + 1]));
#pragma unroll
      for (int s4 = 0; s4 < 8; s4 += 4) {
        asm volatile("v_permlane32_swap_b32 %0, %1" : "+v"(W[s4 + 0]), "+v"(W[s4 + 2]));
        asm volatile("v_permlane32_swap_b32 %0, %1" : "+v"(W[s4 + 1]), "+v"(W[s4 + 3]));
      }
      // ---- PV: O^T = V^T x P^T
      __builtin_amdgcn_s_setprio(1);
#pragma unroll
      for (int dt = 0; dt < 4; dt++) {
        int r = dt * 8 + (l31 >> 2);
        int clb = 4 * (l31 & 3) + h;
        f32x16 a = acc[dt];
#pragma unroll
        for (int ks = 0; ks < 2; ks++) {
          int cl = clb + 2 * ks;
          bf16x8 vf = *(const bf16x8*)(vcur + r * 256 + ((cl ^ (r & 15)) << 4));
          union { uint32_t u[4]; bf16x8 v; } pb;
          pb.u[0] = W[ks * 4 + 0];
          pb.u[1] = W[ks * 4 + 1];
          pb.u[2] = W[ks * 4 + 2];
          pb.u[3] = W[ks * 4 + 3];
          a = MFMA32(vf, pb.v, a);
        }
        acc[dt] = a;
      }
      __builtin_amdgcn_s_setprio(0);
    }
    __syncthreads();  // staging of next chunk complete + buffer handoff
    cur ^= 1;
  }
  // ---- merge: group 1 -> LDS, group 0 combines + stores
  if (grp == 1) {
    char* reg = ldsbuf + wid4 * 16384 + lane * 256;
#pragma unroll
    for (int dt = 0; dt < 4; dt++) {
      union { f32x16 v; f32x4 q[4]; } u;
      u.v = acc[dt];
#pragma unroll
      for (int uu = 0; uu < 4; uu++)
        *(f32x4*)(reg + (((dt * 4 + uu) ^ (lane & 15)) << 4)) = u.q[uu];
    }
    ml1[wid4][lane][0] = mr;
    ml1[wid4][lane][1] = lr;
  }
  __syncthreads();
  if (grp == 0) {
    float m1 = ml1[wid4][lane][0], l1 = ml1[wid4][lane][1];
    float m = fmaxf(mr, m1);
    float f0 = exp2f(mr - m), f1 = exp2f(m1 - m);
    float linv = 1.0f / (lr * f0 + l1 * f1);
    char* reg = ldsbuf + wid4 * 16384 + lane * 256;
    int q = qw + l31;
    size_t base = ((size_t)(b * L_ + q) * H_ + hh) * D_ + 4 * h;
#pragma unroll
    for (int dt = 0; dt < 4; dt++) {
      union { f32x16 v; f32x4 q[4]; } u;
      u.v = acc[dt];
#pragma unroll
      for (int uu = 0; uu < 4; uu++) {
        f32x4 a1 = *(f32x4*)(reg + (((dt * 4 + uu) ^ (lane & 15)) << 4));
        bf16x4 o;
#pragma unroll
        for (int e = 0; e < 4; e++)
          o[e] = (bf16)((u.q[uu][e] * f0 + a1[e] * f1) * linv);
        *(bf16x4*)(attnout + base + dt * 32 + 8 * uu) = o;
      }
    }
  }
}

extern "C" void kernel_launch(void* const* d_in, const int* in_sizes, int n_in,
                              void* d_out, int out_size, void* d_ws, size_t ws_size,
                              hipStream_t stream) {
  const float* x = (const float*)d_in[0];
  const float* wq = (const float*)d_in[1];
  const float* wk = (const float*)d_in[2];
  const float* wv = (const float*)d_in[3];
  const float* wo = (const float*)d_in[4];
  const float* bq = (const float*)d_in[5];
  const float* bk = (const float*)d_in[6];
  const float* bv = (const float*)d_in[7];
  const float* k_cache = (const float*)d_in[8];
  const float* v_cache = (const float*)d_in[9];
  const int* offp = (const int*)d_in[10];

  char* w = (char*)d_ws;
  size_t off = 0;
  auto alloc = [&](size_t bytes) -> char* {
    char* p = w + off;
    off += (bytes + 255) & ~(size_t)255;
    return p;
  };
  const size_t nBLE = (size_t)B_ * L_ * E_;
  const size_t nBLKV = (size_t)B_ * L_ * EKV_;
  const size_t nKV = (size_t)B_ * HKV_ * S_ * D_;
  bf16* xb = (bf16*)alloc(nBLE * 2);
  bf16* wqb = (bf16*)alloc((size_t)E_ * E_ * 2);
  bf16* wkb = (bf16*)alloc((size_t)EKV_ * E_ * 2);
  bf16* wvb = (bf16*)alloc((size_t)EKV_ * E_ * 2);
  bf16* wob = (bf16*)alloc((size_t)E_ * E_ * 2);
  bf16* q_lin = (bf16*)alloc(nBLE * 2);
  bf16* k_lin = (bf16*)alloc(nBLKV * 2);
  bf16* v_lin = (bf16*)alloc(nBLKV * 2);
  bf16* qbuf = (bf16*)alloc(nBLE * 2);
  bf16* k_all = (bf16*)alloc(nKV * 2);
  bf16* vtall = (bf16*)alloc(nKV * 2);
  bf16* attnout = (bf16*)alloc(nBLE * 2);
  float2* trig = (float2*)alloc((size_t)L_ * 64 * sizeof(float2));

  cvt_kernel<<<(int)(nBLE / 1024), 256, 0, stream>>>(x, xb, (int)nBLE);
  cvt_kernel<<<(int)((size_t)E_ * E_ / 1024), 256, 0, stream>>>(wq, wqb, E_ * E_);
  cvt_kernel<<<(int)((size_t)EKV_ * E_ / 1024), 256, 0, stream>>>(wk, wkb, EKV_ * E_);
  cvt_kernel<<<(int)((size_t)EKV_ * E_ / 1024), 256, 0, stream>>>(wv, wvb, EKV_ * E_);
  cvt_kernel<<<(int)((size_t)E_ * E_ / 1024), 256, 0, stream>>>(wo, wob, E_ * E_);
  trig_kernel<<<L_, 64, 0, stream>>>(offp, trig);

  const int M = B_ * L_;  // 4096
  gemm_nt<0><<<dim3(M / 128, E_ / 128), 256, 0, stream>>>(xb, wqb, bq, q_lin, M, E_, E_);
  gemm_nt<0><<<dim3(M / 128, EKV_ / 128), 256, 0, stream>>>(xb, wkb, bk, k_lin, M, EKV_, E_);
  gemm_nt<0><<<dim3(M / 128, EKV_ / 128), 256, 0, stream>>>(xb, wvb, bv, v_lin, M, EKV_, E_);
  rope_q_kernel<<<B_ * L_ / 2, 256, 0, stream>>>(q_lin, trig, qbuf);
  build_k_kernel<<<dim3(S_, B_ * HKV_), 128, 0, stream>>>(k_cache, k_lin, trig, k_all);
  build_vt_kernel<<<dim3(S_ / 64, D_ / 64, B_ * HKV_), 256, 0, stream>>>(v_cache, v_lin, vtall);
  attn_kernel<<<dim3(16, 32), 512, 0, stream>>>(qbuf, k_all, vtall, attnout);
  gemm_nt<1><<<dim3(M / 128, E_ / 128), 256, 0, stream>>>(attnout, wob, nullptr, d_out, M, E_, E_);
}

// Round 8
// 391.711 us; speedup vs baseline: 1.2224x; 1.2224x over previous
//
#include <hip/hip_runtime.h>
#include <hip/hip_bf16.h>
#include <stdint.h>

typedef __bf16 bf16;
typedef __bf16 bf16x8 __attribute__((ext_vector_type(8)));
typedef __bf16 bf16x4 __attribute__((ext_vector_type(4)));
typedef float f32x4 __attribute__((ext_vector_type(4)));
typedef float f32x16 __attribute__((ext_vector_type(16)));

#define B_ 2
#define L_ 2048
#define E_ 2048
#define H_ 16
#define HKV_ 2
#define G_ 8
#define D_ 128
#define SPAST_ 2048
#define S_ 4096
#define EKV_ 256

#define MFMA16(a, b, c) __builtin_amdgcn_mfma_f32_16x16x32_bf16(a, b, c, 0, 0, 0)
#define MFMA32(a, b, c) __builtin_amdgcn_mfma_f32_32x32x16_bf16(a, b, c, 0, 0, 0)

__device__ __forceinline__ void gload16(const bf16* g, bf16* l) {
  __builtin_amdgcn_global_load_lds(
      (__attribute__((address_space(1))) void*)g,
      (__attribute__((address_space(3))) void*)l, 16, 0, 0);
}

// ---------------- f32 -> bf16 conversion ----------------
__global__ void cvt_kernel(const float* __restrict__ src, bf16* __restrict__ dst, int n) {
  int i = (blockIdx.x * 256 + threadIdx.x) * 4;
  if (i >= n) return;
  float4 v = *(const float4*)(src + i);
  bf16x4 o;
  o[0] = (bf16)v.x; o[1] = (bf16)v.y; o[2] = (bf16)v.z; o[3] = (bf16)v.w;
  *(bf16x4*)(dst + i) = o;
}

// ---------------- trig table ----------------
__global__ void trig_kernel(const int* __restrict__ offp, float2* __restrict__ trig) {
  int l = blockIdx.x, j = threadIdx.x;  // 64 threads
  float inv = exp2f(-(float)j * (13.287712379549449f / 64.0f));  // log2(10000)
  float ang = (float)(*offp + l) * inv;
  trig[l * 64 + j] = make_float2(cosf(ang), sinf(ang));
}

// ---------------- NT GEMM: C(M,N) = A(M,K) @ Bw(N,K)^T + bias ----------------
template <int OUTF32>
__global__ __launch_bounds__(256) void gemm_nt(const bf16* __restrict__ A,
                                               const bf16* __restrict__ Bw,
                                               const float* __restrict__ bias,
                                               void* __restrict__ Cout,
                                               int M, int N, int K) {
  __shared__ bf16 As[128 * 64];
  __shared__ bf16 Bs[128 * 64];
  const int tid = threadIdx.x;
  const int wid = tid >> 6, lane = tid & 63;
  const int ln15 = lane & 15, lq = lane >> 4;
  const int row0 = blockIdx.x * 128, col0 = blockIdx.y * 128;
  const int wr = wid >> 1, wc = wid & 1;
  f32x4 acc[4][4] = {};
  char* AsB = (char*)As;
  char* BsB = (char*)Bs;
  for (int k0 = 0; k0 < K; k0 += 64) {
#pragma unroll
    for (int j = 0; j < 4; j++) {
      int cid = j * 256 + tid;
      int r = cid >> 3, c = cid & 7;
      int csw = (c ^ (r & 7)) << 3;
      gload16(A + (size_t)(row0 + r) * K + k0 + csw, (bf16*)(AsB + (j * 256 + wid * 64) * 16));
      gload16(Bw + (size_t)(col0 + r) * K + k0 + csw, (bf16*)(BsB + (j * 256 + wid * 64) * 16));
    }
    __syncthreads();
    bf16x8 af[4][2], bfm[4][2];
#pragma unroll
    for (int m = 0; m < 4; m++) {
#pragma unroll
      for (int kk = 0; kk < 2; kk++) {
        int Ra = wr * 64 + m * 16 + ln15;
        int Rb = wc * 64 + m * 16 + ln15;
        int c = (kk << 2) + lq;
        af[m][kk] = *(const bf16x8*)(AsB + Ra * 128 + ((c ^ (Ra & 7)) << 4));
        bfm[m][kk] = *(const bf16x8*)(BsB + Rb * 128 + ((c ^ (Rb & 7)) << 4));
      }
    }
#pragma unroll
    for (int m = 0; m < 4; m++)
#pragma unroll
      for (int n = 0; n < 4; n++)
#pragma unroll
        for (int kk = 0; kk < 2; kk++)
          acc[m][n] = MFMA16(af[m][kk], bfm[n][kk], acc[m][n]);
    __syncthreads();
  }
#pragma unroll
  for (int m = 0; m < 4; m++) {
    int gr0 = row0 + wr * 64 + m * 16 + 4 * lq;
#pragma unroll
    for (int n = 0; n < 4; n++) {
      int gc = col0 + wc * 64 + n * 16 + ln15;
      float bv = bias ? bias[gc] : 0.0f;
#pragma unroll
      for (int reg = 0; reg < 4; reg++) {
        float v = acc[m][n][reg] + bv;
        size_t idx = (size_t)(gr0 + reg) * N + gc;
        if (OUTF32)
          ((float*)Cout)[idx] = v;
        else
          ((bf16*)Cout)[idx] = (bf16)v;
      }
    }
  }
}

// ---------------- RoPE on Q (vectorized bf16x8), fold softmax scale*log2e ----------------
__global__ void rope_q_kernel(const bf16* __restrict__ q_lin, const float2* __restrict__ trig,
                              bf16* __restrict__ qbuf) {
  int bl = blockIdx.x * 2 + (threadIdx.x >> 7);  // grid = B*L/2
  int b = bl >> 11, l = bl & 2047;
  int u = threadIdx.x & 127;
  int h = u >> 3, j0 = (u & 7) * 8;
  const float QS = 0.08838834764831845f * 1.4426950408889634f;  // 1/sqrt(128) * log2(e)
  const bf16* src = q_lin + (size_t)bl * E_ + h * D_ + j0;
  bf16x8 x1 = *(const bf16x8*)(src);
  bf16x8 x2 = *(const bf16x8*)(src + 64);
  bf16x8 o1, o2;
#pragma unroll
  for (int e = 0; e < 8; e++) {
    float2 cs = trig[l * 64 + j0 + e];
    float a = (float)x1[e], c = (float)x2[e];
    o1[e] = (bf16)((a * cs.x - c * cs.y) * QS);
    o2[e] = (bf16)((c * cs.x + a * cs.y) * QS);
  }
  size_t o = ((size_t)(b * H_ + h) * L_ + l) * D_ + j0;
  *(bf16x8*)(qbuf + o) = o1;
  *(bf16x8*)(qbuf + o + 64) = o2;
}

// ---------------- build k_all (B,HKV,S,D) ----------------
__global__ void build_k_kernel(const float* __restrict__ k_cache, const bf16* __restrict__ k_lin,
                               const float2* __restrict__ trig, bf16* __restrict__ k_all) {
  int d = threadIdx.x;  // 128
  int s = blockIdx.x;
  int bz = blockIdx.y;  // b*HKV + hkv
  size_t oidx = ((size_t)bz * S_ + s) * D_ + d;
  if (s < SPAST_) {
    k_all[oidx] = (bf16)k_cache[((size_t)bz * SPAST_ + s) * D_ + d];
  } else {
    int l = s - SPAST_;
    int b = bz >> 1, kh = bz & 1;
    int j = d & 63;
    float2 cs = trig[l * 64 + j];
    size_t base = (size_t)(b * L_ + l) * EKV_ + kh * D_;
    float x1 = (float)k_lin[base + j];
    float x2 = (float)k_lin[base + 64 + j];
    float v = (d < 64) ? (x1 * cs.x - x2 * cs.y) : (x2 * cs.x + x1 * cs.y);
    k_all[oidx] = (bf16)v;
  }
}

// ---------------- build transposed V: vtall (B,HKV,D,S) (vectorized) ----------------
__global__ void build_vt_kernel(const float* __restrict__ v_cache, const bf16* __restrict__ v_lin,
                                bf16* __restrict__ vtall) {
  __shared__ float tile[64][68];
  int s0 = blockIdx.x * 64;
  int d0 = blockIdx.y * 64;
  int bz = blockIdx.z;
  int b = bz >> 1, kh = bz & 1;
#pragma unroll
  for (int it = 0; it < 4; it++) {
    int idx = it * 256 + threadIdx.x;  // 0..1023
    int ss = idx >> 4, dd0 = (idx & 15) * 4;
    int s = s0 + ss;
    float4 v;
    if (s < SPAST_) {
      v = *(const float4*)(v_cache + ((size_t)bz * SPAST_ + s) * D_ + d0 + dd0);
    } else {
      bf16x4 t = *(const bf16x4*)(v_lin + (size_t)(b * L_ + (s - SPAST_)) * EKV_ + kh * D_ + d0 + dd0);
      v = make_float4((float)t[0], (float)t[1], (float)t[2], (float)t[3]);
    }
    tile[ss][dd0] = v.x; tile[ss][dd0 + 1] = v.y;
    tile[ss][dd0 + 2] = v.z; tile[ss][dd0 + 3] = v.w;
  }
  __syncthreads();
#pragma unroll
  for (int it = 0; it < 4; it++) {
    int idx = it * 256 + threadIdx.x;
    int dd = idx >> 4, ss0 = (idx & 15) * 4;
    bf16x4 o;
#pragma unroll
    for (int e = 0; e < 4; e++) o[e] = (bf16)tile[ss0 + e][dd];
    *(bf16x4*)(vtall + ((size_t)bz * D_ + d0 + dd) * S_ + s0 + ss0) = o;
  }
}

// ---------------- flash attention: split-S 8-wave blocks, 32x32 MFMA, in-register P ----------------
// grid (16, 32) x 512 threads. Waves 0-3 (grp 0) process even 32-key chunks, waves 4-7 (grp 1)
// odd chunks, of the SAME 128 q-rows. Each group has its own dbuf K/V LDS stream (64KB total).
// launch_bounds(512, 2): VGPR budget >=128 (round 7's (512,4) forced a 64-reg budget -> acc/qf
// spilled to scratch, 6x HBM traffic). Natural pressure ~110-125 -> no spill, and VGPR<=128 +
// LDS 66KB lets 2 blocks/CU co-reside = 4 waves/SIMD.
__global__ __launch_bounds__(512, 2) void attn_kernel(const bf16* __restrict__ qbuf,
                                                      const bf16* __restrict__ k_all,
                                                      const bf16* __restrict__ vtall,
                                                      bf16* __restrict__ attnout) {
  __shared__ char ldsbuf[65536];     // [grp][K|V][buf][8KB]
  __shared__ float ml1[4][64][2];    // group-1 (m,l) for merge
  const int tid = threadIdx.x;
  const int wid = tid >> 6, lane = tid & 63;
  const int grp = wid >> 2, wid4 = wid & 3;
  const int l31 = lane & 31, h = lane >> 5;
  // balance remap: co-resident blocks (x,y),(x,y+16) -> q-blocks x, 15-x (constant sum)
  const int xq = ((blockIdx.y >> 4) & 1) ? (15 - (int)blockIdx.x) : (int)blockIdx.x;
  const int q0 = xq * 128;
  const int bh = blockIdx.y;
  const int b = bh / H_, hh = bh % H_;
  const int hkv = hh / G_;
  const bf16* kb = k_all + (size_t)(b * HKV_ + hkv) * S_ * D_;
  const bf16* vb = vtall + (size_t)(b * HKV_ + hkv) * D_ * S_;
  const int qw = q0 + wid4 * 32;  // wave's q base (groups share q-rows)
  // per-thread staging source rows (t8 = position within group)
  const int t8 = (wid4 << 6) | lane;            // 0..255
  const int r0 = t8 >> 4;                        // 0..15
  const int cl0 = (t8 & 15) ^ (r0 & 15);         // logical 16B slot
  const bf16* krow = kb + r0 * D_ + cl0 * 8;                           // + s0*D [+16*D]
  const bf16* vrow = vb + (size_t)(4 * r0 + (cl0 >> 2)) * S_ + (cl0 & 3) * 8;  // + s0 [+64*S]
  char* kbase = ldsbuf + grp * 16384;
  char* vbase = ldsbuf + 32768 + grp * 16384;
  const int dstoff = (wid4 * 64) * 16;
  // Q fragments (B operand): col=q=l31, k-dim d = ks*16 + 8h + i
  bf16x8 qf[8];
  {
    const bf16* qp = qbuf + ((size_t)(b * H_ + hh) * L_ + qw + l31) * D_ + h * 8;
#pragma unroll
    for (int ks = 0; ks < 8; ks++) qf[ks] = *(const bf16x8*)(qp + ks * 16);
  }
  f32x16 acc[4] = {};
  float mr = -3e38f, lr = 0.f;

  auto STAGE = [&](int buf, int s0) {
    char* kd = kbase + buf * 8192 + dstoff;
    char* vd = vbase + buf * 8192 + dstoff;
    size_t ko = (size_t)s0 << 7;  // s0 * D_
    gload16(krow + ko, (bf16*)(kd));
    gload16(krow + ko + 16 * D_, (bf16*)(kd + 4096));
    gload16(vrow + s0, (bf16*)(vd));
    gload16(vrow + s0 + (size_t)64 * S_, (bf16*)(vd + 4096));
  };

  const int nch = (q0 + 128 + SPAST_) >> 5;  // 32-key chunks; always even (68+4xq)
  const int rounds = nch >> 1;               // chunks per group
  const int smax_w = qw + 32 + SPAST_;

  STAGE(0, grp << 5);  // group g: chunk g
  __syncthreads();
  int cur = 0;
  for (int i = 0; i < rounds; ++i) {
    const int s0 = ((i << 1) + grp) << 5;
    if (i + 1 < rounds) STAGE(cur ^ 1, s0 + 64);  // prefetch own next chunk
    if (s0 < smax_w) {
      char* kcur = kbase + cur * 8192;
      char* vcur = vbase + cur * 8192;
      // ---- swapped QK^T: lane holds q=l31, keys s0 + (r&3)+8*(r>>2)+4h, r=0..15
      f32x16 st;
      {
        f32x16 a = {};
        __builtin_amdgcn_s_setprio(1);
#pragma unroll
        for (int ks = 0; ks < 8; ks++) {
          int cl = 2 * ks + h;
          bf16x8 kf = *(const bf16x8*)(kcur + l31 * 256 + ((cl ^ (l31 & 15)) << 4));
          a = MFMA32(kf, qf[ks], a);
        }
        __builtin_amdgcn_s_setprio(0);
        st = a;
      }
      // ---- causal mask (only diagonal chunks trigger)
      if (s0 + 31 > qw + SPAST_) {
        int q = qw + l31;
#pragma unroll
        for (int r = 0; r < 16; r++) {
          int key = s0 + (r & 3) + 8 * (r >> 2) + 4 * h;
          if (key > q + SPAST_) st[r] = -1e30f;
        }
      }
      // ---- online softmax: in-lane tree + 1 half-swap
      float mt = fmaxf(st[0], st[1]);
#pragma unroll
      for (int r = 2; r < 16; r++) mt = fmaxf(mt, st[r]);
      mt = fmaxf(mt, __shfl_xor(mt, 32));
      if (__any(mt - mr > 8.0f)) {  // T13 defer-max
        float mn = fmaxf(mr, mt);
        float fac = exp2f(mr - mn);
        mr = mn;
        lr *= fac;
#pragma unroll
        for (int dt = 0; dt < 4; dt++) acc[dt] *= fac;
      }
      float s = 0.f;
#pragma unroll
      for (int r = 0; r < 16; r++) {
        float p = exp2f(st[r] - mr);
        st[r] = p;
        s += p;
      }
      s += __shfl_xor(s, 32);
      lr += s;
      // ---- P -> bf16 dwords + permlane32_swap (VDST.hi <-> VSRC.lo)
      uint32_t W[8];
#pragma unroll
      for (int j = 0; j < 8; j++)
        asm("v_cvt_pk_bf16_f32 %0, %1, %2" : "=v"(W[j]) : "v"(st[2 * j]), "v"(st[2 * j + 1]));
#pragma unroll
      for (int s4 = 0; s4 < 8; s4 += 4) {
        asm volatile("v_permlane32_swap_b32 %0, %1" : "+v"(W[s4 + 0]), "+v"(W[s4 + 2]));
        asm volatile("v_permlane32_swap_b32 %0, %1" : "+v"(W[s4 + 1]), "+v"(W[s4 + 3]));
      }
      // ---- PV: O^T = V^T x P^T
      __builtin_amdgcn_s_setprio(1);
#pragma unroll
      for (int dt = 0; dt < 4; dt++) {
        int r = dt * 8 + (l31 >> 2);
        int clb = 4 * (l31 & 3) + h;
        f32x16 a = acc[dt];
#pragma unroll
        for (int ks = 0; ks < 2; ks++) {
          int cl = clb + 2 * ks;
          bf16x8 vf = *(const bf16x8*)(vcur + r * 256 + ((cl ^ (r & 15)) << 4));
          union { uint32_t u[4]; bf16x8 v; } pb;
          pb.u[0] = W[ks * 4 + 0];
          pb.u[1] = W[ks * 4 + 1];
          pb.u[2] = W[ks * 4 + 2];
          pb.u[3] = W[ks * 4 + 3];
          a = MFMA32(vf, pb.v, a);
        }
        acc[dt] = a;
      }
      __builtin_amdgcn_s_setprio(0);
    }
    __syncthreads();  // staging of next chunk complete + buffer handoff
    cur ^= 1;
  }
  // ---- merge: group 1 -> LDS, group 0 combines + stores
  if (grp == 1) {
    char* reg = ldsbuf + wid4 * 16384 + lane * 256;
#pragma unroll
    for (int dt = 0; dt < 4; dt++) {
      union { f32x16 v; f32x4 q[4]; } u;
      u.v = acc[dt];
#pragma unroll
      for (int uu = 0; uu < 4; uu++)
        *(f32x4*)(reg + (((dt * 4 + uu) ^ (lane & 15)) << 4)) = u.q[uu];
    }
    ml1[wid4][lane][0] = mr;
    ml1[wid4][lane][1] = lr;
  }
  __syncthreads();
  if (grp == 0) {
    float m1 = ml1[wid4][lane][0], l1 = ml1[wid4][lane][1];
    float m = fmaxf(mr, m1);
    float f0 = exp2f(mr - m), f1 = exp2f(m1 - m);
    float linv = 1.0f / (lr * f0 + l1 * f1);
    char* reg = ldsbuf + wid4 * 16384 + lane * 256;
    int q = qw + l31;
    size_t base = ((size_t)(b * L_ + q) * H_ + hh) * D_ + 4 * h;
#pragma unroll
    for (int dt = 0; dt < 4; dt++) {
      union { f32x16 v; f32x4 q[4]; } u;
      u.v = acc[dt];
#pragma unroll
      for (int uu = 0; uu < 4; uu++) {
        f32x4 a1 = *(f32x4*)(reg + (((dt * 4 + uu) ^ (lane & 15)) << 4));
        bf16x4 o;
#pragma unroll
        for (int e = 0; e < 4; e++)
          o[e] = (bf16)((u.q[uu][e] * f0 + a1[e] * f1) * linv);
        *(bf16x4*)(attnout + base + dt * 32 + 8 * uu) = o;
      }
    }
  }
}

extern "C" void kernel_launch(void* const* d_in, const int* in_sizes, int n_in,
                              void* d_out, int out_size, void* d_ws, size_t ws_size,
                              hipStream_t stream) {
  const float* x = (const float*)d_in[0];
  const float* wq = (const float*)d_in[1];
  const float* wk = (const float*)d_in[2];
  const float* wv = (const float*)d_in[3];
  const float* wo = (const float*)d_in[4];
  const float* bq = (const float*)d_in[5];
  const float* bk = (const float*)d_in[6];
  const float* bv = (const float*)d_in[7];
  const float* k_cache = (const float*)d_in[8];
  const float* v_cache = (const float*)d_in[9];
  const int* offp = (const int*)d_in[10];

  char* w = (char*)d_ws;
  size_t off = 0;
  auto alloc = [&](size_t bytes) -> char* {
    char* p = w + off;
    off += (bytes + 255) & ~(size_t)255;
    return p;
  };
  const size_t nBLE = (size_t)B_ * L_ * E_;
  const size_t nBLKV = (size_t)B_ * L_ * EKV_;
  const size_t nKV = (size_t)B_ * HKV_ * S_ * D_;
  bf16* xb = (bf16*)alloc(nBLE * 2);
  bf16* wqb = (bf16*)alloc((size_t)E_ * E_ * 2);
  bf16* wkb = (bf16*)alloc((size_t)EKV_ * E_ * 2);
  bf16* wvb = (bf16*)alloc((size_t)EKV_ * E_ * 2);
  bf16* wob = (bf16*)alloc((size_t)E_ * E_ * 2);
  bf16* q_lin = (bf16*)alloc(nBLE * 2);
  bf16* k_lin = (bf16*)alloc(nBLKV * 2);
  bf16* v_lin = (bf16*)alloc(nBLKV * 2);
  bf16* qbuf = (bf16*)alloc(nBLE * 2);
  bf16* k_all = (bf16*)alloc(nKV * 2);
  bf16* vtall = (bf16*)alloc(nKV * 2);
  bf16* attnout = (bf16*)alloc(nBLE * 2);
  float2* trig = (float2*)alloc((size_t)L_ * 64 * sizeof(float2));

  cvt_kernel<<<(int)(nBLE / 1024), 256, 0, stream>>>(x, xb, (int)nBLE);
  cvt_kernel<<<(int)((size_t)E_ * E_ / 1024), 256, 0, stream>>>(wq, wqb, E_ * E_);
  cvt_kernel<<<(int)((size_t)EKV_ * E_ / 1024), 256, 0, stream>>>(wk, wkb, EKV_ * E_);
  cvt_kernel<<<(int)((size_t)EKV_ * E_ / 1024), 256, 0, stream>>>(wv, wvb, EKV_ * E_);
  cvt_kernel<<<(int)((size_t)E_ * E_ / 1024), 256, 0, stream>>>(wo, wob, E_ * E_);
  trig_kernel<<<L_, 64, 0, stream>>>(offp, trig);

  const int M = B_ * L_;  // 4096
  gemm_nt<0><<<dim3(M / 128, E_ / 128), 256, 0, stream>>>(xb, wqb, bq, q_lin, M, E_, E_);
  gemm_nt<0><<<dim3(M / 128, EKV_ / 128), 256, 0, stream>>>(xb, wkb, bk, k_lin, M, EKV_, E_);
  gemm_nt<0><<<dim3(M / 128, EKV_ / 128), 256, 0, stream>>>(xb, wvb, bv, v_lin, M, EKV_, E_);
  rope_q_kernel<<<B_ * L_ / 2, 256, 0, stream>>>(q_lin, trig, qbuf);
  build_k_kernel<<<dim3(S_, B_ * HKV_), 128, 0, stream>>>(k_cache, k_lin, trig, k_all);
  build_vt_kernel<<<dim3(S_ / 64, D_ / 64, B_ * HKV_), 256, 0, stream>>>(v_cache, v_lin, vtall);
  attn_kernel<<<dim3(16, 32), 512, 0, stream>>>(qbuf, k_all, vtall, attnout);
  gemm_nt<1><<<dim3(M / 128, E_ / 128), 256, 0, stream>>>(attnout, wob, nullptr, d_out, M, E_, E_);
}

// Round 9
// 324.414 us; speedup vs baseline: 1.4760x; 1.2074x over previous
//
#include <hip/hip_runtime.h>
#include <hip/hip_bf16.h>
#include <stdint.h>

typedef __bf16 bf16;
typedef __bf16 bf16x8 __attribute__((ext_vector_type(8)));
typedef __bf16 bf16x4 __attribute__((ext_vector_type(4)));
typedef float f32x4 __attribute__((ext_vector_type(4)));
typedef float f32x16 __attribute__((ext_vector_type(16)));

#define B_ 2
#define L_ 2048
#define E_ 2048
#define H_ 16
#define HKV_ 2
#define G_ 8
#define D_ 128
#define SPAST_ 2048
#define S_ 4096
#define EKV_ 256

#define MFMA16(a, b, c) __builtin_amdgcn_mfma_f32_16x16x32_bf16(a, b, c, 0, 0, 0)
#define MFMA32(a, b, c) __builtin_amdgcn_mfma_f32_32x32x16_bf16(a, b, c, 0, 0, 0)

__device__ __forceinline__ void gload16(const bf16* g, bf16* l) {
  __builtin_amdgcn_global_load_lds(
      (__attribute__((address_space(1))) void*)g,
      (__attribute__((address_space(3))) void*)l, 16, 0, 0);
}

// ---------------- f32 -> bf16 conversion ----------------
__global__ void cvt_kernel(const float* __restrict__ src, bf16* __restrict__ dst, int n) {
  int i = (blockIdx.x * 256 + threadIdx.x) * 4;
  if (i >= n) return;
  float4 v = *(const float4*)(src + i);
  bf16x4 o;
  o[0] = (bf16)v.x; o[1] = (bf16)v.y; o[2] = (bf16)v.z; o[3] = (bf16)v.w;
  *(bf16x4*)(dst + i) = o;
}

// ---------------- trig table ----------------
__global__ void trig_kernel(const int* __restrict__ offp, float2* __restrict__ trig) {
  int l = blockIdx.x, j = threadIdx.x;  // 64 threads
  float inv = exp2f(-(float)j * (13.287712379549449f / 64.0f));  // log2(10000)
  float ang = (float)(*offp + l) * inv;
  trig[l * 64 + j] = make_float2(cosf(ang), sinf(ang));
}

// ---------------- NT GEMM: C(M,N) = A(M,K) @ Bw(N,K)^T + bias ----------------
// 128x128 tile, BK=64, 4 waves (2x2). T3 2-phase: double-buffered LDS, STAGE(next)
// issued BEFORE compute, ONE barrier per K-step (was serial stage->sync->compute->sync).
template <int OUTF32>
__global__ __launch_bounds__(256) void gemm_nt(const bf16* __restrict__ A,
                                               const bf16* __restrict__ Bw,
                                               const float* __restrict__ bias,
                                               void* __restrict__ Cout,
                                               int M, int N, int K) {
  __shared__ bf16 As[2 * 128 * 64];
  __shared__ bf16 Bs[2 * 128 * 64];
  const int tid = threadIdx.x;
  const int wid = tid >> 6, lane = tid & 63;
  const int ln15 = lane & 15, lq = lane >> 4;
  const int row0 = blockIdx.x * 128, col0 = blockIdx.y * 128;
  const int wr = wid >> 1, wc = wid & 1;
  f32x4 acc[4][4] = {};
  char* AsB = (char*)As;
  char* BsB = (char*)Bs;

  auto STAGE = [&](int buf, int k0) {
    char* ad = AsB + buf * 16384;
    char* bd = BsB + buf * 16384;
#pragma unroll
    for (int j = 0; j < 4; j++) {
      int cid = j * 256 + tid;
      int r = cid >> 3, c = cid & 7;
      int csw = (c ^ (r & 7)) << 3;
      gload16(A + (size_t)(row0 + r) * K + k0 + csw, (bf16*)(ad + (j * 256 + wid * 64) * 16));
      gload16(Bw + (size_t)(col0 + r) * K + k0 + csw, (bf16*)(bd + (j * 256 + wid * 64) * 16));
    }
  };

  STAGE(0, 0);
  __syncthreads();
  int cur = 0;
  for (int k0 = 0; k0 < K; k0 += 64) {
    if (k0 + 64 < K) STAGE(cur ^ 1, k0 + 64);  // prefetch next K-tile (in flight across compute)
    char* ac = AsB + cur * 16384;
    char* bc = BsB + cur * 16384;
    bf16x8 af[4][2], bfm[4][2];
#pragma unroll
    for (int m = 0; m < 4; m++) {
#pragma unroll
      for (int kk = 0; kk < 2; kk++) {
        int Ra = wr * 64 + m * 16 + ln15;
        int Rb = wc * 64 + m * 16 + ln15;
        int c = (kk << 2) + lq;
        af[m][kk] = *(const bf16x8*)(ac + Ra * 128 + ((c ^ (Ra & 7)) << 4));
        bfm[m][kk] = *(const bf16x8*)(bc + Rb * 128 + ((c ^ (Rb & 7)) << 4));
      }
    }
    __builtin_amdgcn_s_setprio(1);
#pragma unroll
    for (int m = 0; m < 4; m++)
#pragma unroll
      for (int n = 0; n < 4; n++)
#pragma unroll
        for (int kk = 0; kk < 2; kk++)
          acc[m][n] = MFMA16(af[m][kk], bfm[n][kk], acc[m][n]);
    __builtin_amdgcn_s_setprio(0);
    __syncthreads();  // staging complete + all waves done reading cur
    cur ^= 1;
  }
#pragma unroll
  for (int m = 0; m < 4; m++) {
    int gr0 = row0 + wr * 64 + m * 16 + 4 * lq;
#pragma unroll
    for (int n = 0; n < 4; n++) {
      int gc = col0 + wc * 64 + n * 16 + ln15;
      float bv = bias ? bias[gc] : 0.0f;
#pragma unroll
      for (int reg = 0; reg < 4; reg++) {
        float v = acc[m][n][reg] + bv;
        size_t idx = (size_t)(gr0 + reg) * N + gc;
        if (OUTF32)
          ((float*)Cout)[idx] = v;
        else
          ((bf16*)Cout)[idx] = (bf16)v;
      }
    }
  }
}

// ---------------- RoPE on Q (vectorized bf16x8), fold softmax scale*log2e ----------------
__global__ void rope_q_kernel(const bf16* __restrict__ q_lin, const float2* __restrict__ trig,
                              bf16* __restrict__ qbuf) {
  int bl = blockIdx.x * 2 + (threadIdx.x >> 7);  // grid = B*L/2
  int b = bl >> 11, l = bl & 2047;
  int u = threadIdx.x & 127;
  int h = u >> 3, j0 = (u & 7) * 8;
  const float QS = 0.08838834764831845f * 1.4426950408889634f;  // 1/sqrt(128) * log2(e)
  const bf16* src = q_lin + (size_t)bl * E_ + h * D_ + j0;
  bf16x8 x1 = *(const bf16x8*)(src);
  bf16x8 x2 = *(const bf16x8*)(src + 64);
  bf16x8 o1, o2;
#pragma unroll
  for (int e = 0; e < 8; e++) {
    float2 cs = trig[l * 64 + j0 + e];
    float a = (float)x1[e], c = (float)x2[e];
    o1[e] = (bf16)((a * cs.x - c * cs.y) * QS);
    o2[e] = (bf16)((c * cs.x + a * cs.y) * QS);
  }
  size_t o = ((size_t)(b * H_ + h) * L_ + l) * D_ + j0;
  *(bf16x8*)(qbuf + o) = o1;
  *(bf16x8*)(qbuf + o + 64) = o2;
}

// ---------------- build k_all (B,HKV,S,D) ----------------
__global__ void build_k_kernel(const float* __restrict__ k_cache, const bf16* __restrict__ k_lin,
                               const float2* __restrict__ trig, bf16* __restrict__ k_all) {
  int d = threadIdx.x;  // 128
  int s = blockIdx.x;
  int bz = blockIdx.y;  // b*HKV + hkv
  size_t oidx = ((size_t)bz * S_ + s) * D_ + d;
  if (s < SPAST_) {
    k_all[oidx] = (bf16)k_cache[((size_t)bz * SPAST_ + s) * D_ + d];
  } else {
    int l = s - SPAST_;
    int b = bz >> 1, kh = bz & 1;
    int j = d & 63;
    float2 cs = trig[l * 64 + j];
    size_t base = (size_t)(b * L_ + l) * EKV_ + kh * D_;
    float x1 = (float)k_lin[base + j];
    float x2 = (float)k_lin[base + 64 + j];
    float v = (d < 64) ? (x1 * cs.x - x2 * cs.y) : (x2 * cs.x + x1 * cs.y);
    k_all[oidx] = (bf16)v;
  }
}

// ---------------- build transposed V: vtall (B,HKV,D,S) (vectorized) ----------------
__global__ void build_vt_kernel(const float* __restrict__ v_cache, const bf16* __restrict__ v_lin,
                                bf16* __restrict__ vtall) {
  __shared__ float tile[64][68];
  int s0 = blockIdx.x * 64;
  int d0 = blockIdx.y * 64;
  int bz = blockIdx.z;
  int b = bz >> 1, kh = bz & 1;
#pragma unroll
  for (int it = 0; it < 4; it++) {
    int idx = it * 256 + threadIdx.x;  // 0..1023
    int ss = idx >> 4, dd0 = (idx & 15) * 4;
    int s = s0 + ss;
    float4 v;
    if (s < SPAST_) {
      v = *(const float4*)(v_cache + ((size_t)bz * SPAST_ + s) * D_ + d0 + dd0);
    } else {
      bf16x4 t = *(const bf16x4*)(v_lin + (size_t)(b * L_ + (s - SPAST_)) * EKV_ + kh * D_ + d0 + dd0);
      v = make_float4((float)t[0], (float)t[1], (float)t[2], (float)t[3]);
    }
    tile[ss][dd0] = v.x; tile[ss][dd0 + 1] = v.y;
    tile[ss][dd0 + 2] = v.z; tile[ss][dd0 + 3] = v.w;
  }
  __syncthreads();
#pragma unroll
  for (int it = 0; it < 4; it++) {
    int idx = it * 256 + threadIdx.x;
    int dd = idx >> 4, ss0 = (idx & 15) * 4;
    bf16x4 o;
#pragma unroll
    for (int e = 0; e < 4; e++) o[e] = (bf16)tile[ss0 + e][dd];
    *(bf16x4*)(vtall + ((size_t)bz * D_ + d0 + dd) * S_ + s0 + ss0) = o;
  }
}

// ---------------- flash attention (round-6 kernel, best measured: 174 us) ----------------
// grid (16, 32); 4 waves x 32 q-rows (one 32-wide tile each); 64-key chunks dbuf in LDS.
// Swapped QK^T (A=K,B=Q -> S^T): lanes l, l+32 share q=l&31 -> 1 shfl per reduce.
// P stays in registers: cvt_pk_bf16 + v_permlane32_swap build PV B-operands (T12).
// permlane32_swap semantics: VDST[i+32] <-> VSRC[i] (vdst HIGH <-> vsrc LOW).
// 4-bit slot swizzle (c ^ (r&15)) on 256B LDS rows: conflict-free per 16-lane phase.
__global__ __launch_bounds__(256, 2) void attn_kernel(const bf16* __restrict__ qbuf,
                                                      const bf16* __restrict__ k_all,
                                                      const bf16* __restrict__ vtall,
                                                      bf16* __restrict__ attnout) {
  __shared__ bf16 Ks[2 * 64 * 128];   // [key][d], 256B rows, swizzled 16B slots
  __shared__ bf16 Vs[2 * 64 * 128];   // paired rows: row r = {d=2r | d=2r+1}, 256B
  const int tid = threadIdx.x;
  const int wid = tid >> 6, lane = tid & 63;
  const int l31 = lane & 31, h = lane >> 5;
  // balance remap: co-resident blocks (x,y),(x,y+16) -> q-blocks x, 15-x
  const int xq = ((blockIdx.y >> 4) & 1) ? (15 - (int)blockIdx.x) : (int)blockIdx.x;
  const int q0 = xq * 128;
  const int bh = blockIdx.y;
  const int b = bh / H_, hh = bh % H_;
  const int hkv = hh / G_;
  const bf16* kb = k_all + (size_t)(b * HKV_ + hkv) * S_ * D_;
  const bf16* vb = vtall + (size_t)(b * HKV_ + hkv) * D_ * S_;
  const int qw = q0 + wid * 32;  // wave's q base
  // Q fragments (B operand): col=q=l31, k-dim d = ks*16 + 8h + i
  bf16x8 qf[8];
  {
    const bf16* qp = qbuf + ((size_t)(b * H_ + hh) * L_ + qw + l31) * D_ + h * 8;
#pragma unroll
    for (int ks = 0; ks < 8; ks++) qf[ks] = *(const bf16x8*)(qp + ks * 16);
  }
  f32x16 acc[4] = {};
  float mr = -3e38f, lr = 0.f;

  auto STAGE = [&](int buf, int s0) {
    char* kd = (char*)Ks + buf * 16384;
    char* vd = (char*)Vs + buf * 16384;
#pragma unroll
    for (int j = 0; j < 4; j++) {
      int cid = j * 256 + tid;
      int r = cid >> 4;
      int cl = (cid & 15) ^ (r & 15);  // logical slot stored at this linear pos
      // K: row r = key, slot cl -> d elems cl*8
      gload16(kb + (size_t)(s0 + r) * D_ + cl * 8, (bf16*)(kd + (j * 256 + wid * 64) * 16));
      // V: row r = d-pair; cl -> d = 2r + (cl>>3), keys (cl&7)*8
      gload16(vb + (size_t)(2 * r + (cl >> 3)) * S_ + s0 + (cl & 7) * 8,
              (bf16*)(vd + (j * 256 + wid * 64) * 16));
    }
  };

  const int nchunk = (q0 + 128 + SPAST_) >> 6;  // block-uniform
  const int smax_w = qw + 32 + SPAST_;

  STAGE(0, 0);
  __syncthreads();
  int cur = 0;
  for (int sc = 0; sc < nchunk; ++sc) {
    int s0 = sc << 6;
    if (sc + 1 < nchunk) STAGE(cur ^ 1, s0 + 64);  // prefetch next chunk
    if (s0 < smax_w) {
      char* kcur = (char*)Ks + cur * 16384;
      char* vcur = (char*)Vs + cur * 16384;
      // ---- swapped QK^T: st[t]; lane: q=l31, keys t*32+(r&3)+8*(r>>2)+4h
      f32x16 st[2];
      __builtin_amdgcn_s_setprio(1);
#pragma unroll
      for (int t = 0; t < 2; t++) {
        f32x16 a = {};
        int R = t * 32 + l31;
#pragma unroll
        for (int ks = 0; ks < 8; ks++) {
          int cl = 2 * ks + h;
          bf16x8 kf = *(const bf16x8*)(kcur + R * 256 + ((cl ^ (R & 15)) << 4));
          a = MFMA32(kf, qf[ks], a);
        }
        st[t] = a;
      }
      __builtin_amdgcn_s_setprio(0);
      // ---- causal mask (only diagonal chunks trigger)
      if (s0 + 63 > qw + SPAST_) {
        int q = qw + l31;
#pragma unroll
        for (int t = 0; t < 2; t++)
#pragma unroll
          for (int r = 0; r < 16; r++) {
            int key = s0 + t * 32 + (r & 3) + 8 * (r >> 2) + 4 * h;
            if (key > q + SPAST_) st[t][r] = -1e30f;
          }
      }
      // ---- online softmax: in-lane tree + 1 half-swap
      float mt = fmaxf(st[0][0], st[0][1]);
#pragma unroll
      for (int r = 2; r < 16; r++) mt = fmaxf(mt, st[0][r]);
#pragma unroll
      for (int r = 0; r < 16; r++) mt = fmaxf(mt, st[1][r]);
      mt = fmaxf(mt, __shfl_xor(mt, 32));
      if (__any(mt - mr > 8.0f)) {  // T13 defer-max
        float mn = fmaxf(mr, mt);
        float fac = exp2f(mr - mn);
        mr = mn;
        lr *= fac;
#pragma unroll
        for (int dt = 0; dt < 4; dt++) acc[dt] *= fac;
      }
      float s = 0.f;
#pragma unroll
      for (int t = 0; t < 2; t++)
#pragma unroll
        for (int r = 0; r < 16; r++) {
          float p = exp2f(st[t][r] - mr);
          st[t][r] = p;
          s += p;
        }
      s += __shfl_xor(s, 32);
      lr += s;
      // ---- P -> bf16 dwords + permlane32_swap (VDST.hi <-> VSRC.lo)
      uint32_t W[2][8];
#pragma unroll
      for (int t = 0; t < 2; t++)
#pragma unroll
        for (int j = 0; j < 8; j++)
          asm("v_cvt_pk_bf16_f32 %0, %1, %2"
              : "=v"(W[t][j])
              : "v"(st[t][2 * j]), "v"(st[t][2 * j + 1]));
#pragma unroll
      for (int t = 0; t < 2; t++)
#pragma unroll
        for (int s4 = 0; s4 < 8; s4 += 4) {
          asm volatile("v_permlane32_swap_b32 %0, %1" : "+v"(W[t][s4 + 0]), "+v"(W[t][s4 + 2]));
          asm volatile("v_permlane32_swap_b32 %0, %1" : "+v"(W[t][s4 + 1]), "+v"(W[t][s4 + 3]));
        }
      // ---- PV: O^T = V^T x P^T; A-frag from paired-row V LDS
      __builtin_amdgcn_s_setprio(1);
#pragma unroll
      for (int dt = 0; dt < 4; dt++) {
        int r = dt * 16 + (l31 >> 1);
        int clb = 8 * (l31 & 1) + h;
        f32x16 a = acc[dt];
#pragma unroll
        for (int ks = 0; ks < 4; ks++) {
          int cl = clb + 2 * ks;
          bf16x8 vf = *(const bf16x8*)(vcur + r * 256 + ((cl ^ (r & 15)) << 4));
          union { uint32_t u[4]; bf16x8 v; } pb;
          pb.u[0] = W[ks >> 1][(ks & 1) * 4 + 0];
          pb.u[1] = W[ks >> 1][(ks & 1) * 4 + 1];
          pb.u[2] = W[ks >> 1][(ks & 1) * 4 + 2];
          pb.u[3] = W[ks >> 1][(ks & 1) * 4 + 3];
          a = MFMA32(vf, pb.v, a);
        }
        acc[dt] = a;
      }
      __builtin_amdgcn_s_setprio(0);
    }
    __syncthreads();  // staging of next chunk complete + buffer handoff
    cur ^= 1;
  }
  // ---- epilogue: lane holds O[q=l31][d = dt*32+8u+4h+e] -> 8B stores
  {
    float inv = 1.0f / lr;
    int q = qw + l31;
    size_t base = ((size_t)(b * L_ + q) * H_ + hh) * D_;
#pragma unroll
    for (int dt = 0; dt < 4; dt++)
#pragma unroll
      for (int u = 0; u < 4; u++) {
        bf16x4 o;
#pragma unroll
        for (int e = 0; e < 4; e++) o[e] = (bf16)(acc[dt][4 * u + e] * inv);
        *(bf16x4*)(attnout + base + dt * 32 + 8 * u + 4 * h) = o;
      }
  }
}

extern "C" void kernel_launch(void* const* d_in, const int* in_sizes, int n_in,
                              void* d_out, int out_size, void* d_ws, size_t ws_size,
                              hipStream_t stream) {
  const float* x = (const float*)d_in[0];
  const float* wq = (const float*)d_in[1];
  const float* wk = (const float*)d_in[2];
  const float* wv = (const float*)d_in[3];
  const float* wo = (const float*)d_in[4];
  const float* bq = (const float*)d_in[5];
  const float* bk = (const float*)d_in[6];
  const float* bv = (const float*)d_in[7];
  const float* k_cache = (const float*)d_in[8];
  const float* v_cache = (const float*)d_in[9];
  const int* offp = (const int*)d_in[10];

  char* w = (char*)d_ws;
  size_t off = 0;
  auto alloc = [&](size_t bytes) -> char* {
    char* p = w + off;
    off += (bytes + 255) & ~(size_t)255;
    return p;
  };
  const size_t nBLE = (size_t)B_ * L_ * E_;
  const size_t nBLKV = (size_t)B_ * L_ * EKV_;
  const size_t nKV = (size_t)B_ * HKV_ * S_ * D_;
  bf16* xb = (bf16*)alloc(nBLE * 2);
  bf16* wqb = (bf16*)alloc((size_t)E_ * E_ * 2);
  bf16* wkb = (bf16*)alloc((size_t)EKV_ * E_ * 2);
  bf16* wvb = (bf16*)alloc((size_t)EKV_ * E_ * 2);
  bf16* wob = (bf16*)alloc((size_t)E_ * E_ * 2);
  bf16* q_lin = (bf16*)alloc(nBLE * 2);
  bf16* k_lin = (bf16*)alloc(nBLKV * 2);
  bf16* v_lin = (bf16*)alloc(nBLKV * 2);
  bf16* qbuf = (bf16*)alloc(nBLE * 2);
  bf16* k_all = (bf16*)alloc(nKV * 2);
  bf16* vtall = (bf16*)alloc(nKV * 2);
  bf16* attnout = (bf16*)alloc(nBLE * 2);
  float2* trig = (float2*)alloc((size_t)L_ * 64 * sizeof(float2));

  cvt_kernel<<<(int)(nBLE / 1024), 256, 0, stream>>>(x, xb, (int)nBLE);
  cvt_kernel<<<(int)((size_t)E_ * E_ / 1024), 256, 0, stream>>>(wq, wqb, E_ * E_);
  cvt_kernel<<<(int)((size_t)EKV_ * E_ / 1024), 256, 0, stream>>>(wk, wkb, EKV_ * E_);
  cvt_kernel<<<(int)((size_t)EKV_ * E_ / 1024), 256, 0, stream>>>(wv, wvb, EKV_ * E_);
  cvt_kernel<<<(int)((size_t)E_ * E_ / 1024), 256, 0, stream>>>(wo, wob, E_ * E_);
  trig_kernel<<<L_, 64, 0, stream>>>(offp, trig);

  const int M = B_ * L_;  // 4096
  gemm_nt<0><<<dim3(M / 128, E_ / 128), 256, 0, stream>>>(xb, wqb, bq, q_lin, M, E_, E_);
  gemm_nt<0><<<dim3(M / 128, EKV_ / 128), 256, 0, stream>>>(xb, wkb, bk, k_lin, M, EKV_, E_);
  gemm_nt<0><<<dim3(M / 128, EKV_ / 128), 256, 0, stream>>>(xb, wvb, bv, v_lin, M, EKV_, E_);
  rope_q_kernel<<<B_ * L_ / 2, 256, 0, stream>>>(q_lin, trig, qbuf);
  build_k_kernel<<<dim3(S_, B_ * HKV_), 128, 0, stream>>>(k_cache, k_lin, trig, k_all);
  build_vt_kernel<<<dim3(S_ / 64, D_ / 64, B_ * HKV_), 256, 0, stream>>>(v_cache, v_lin, vtall);
  attn_kernel<<<dim3(16, 32), 256, 0, stream>>>(qbuf, k_all, vtall, attnout);
  gemm_nt<1><<<dim3(M / 128, E_ / 128), 256, 0, stream>>>(attnout, wob, nullptr, d_out, M, E_, E_);
}